// Round 1
// baseline (160.163 us; speedup 1.0000x reference)
//
#include <hip/hip_runtime.h>
#include <stdint.h>

// Problem constants (AWQGemm: x[1024,4096] fp32, qweight[4096,1376] i32,
// scales[32,11008] fp32, qzeros[32,1376] i32 -> C[1024,11008] fp32)
#define M_DIM 1024
#define K_DIM 4096
#define N_DIM 11008
#define NC_DIM 1376   // N/8
#define G_DIM 32
#define GS 128

typedef __bf16 bf16x8 __attribute__((ext_vector_type(8)));
typedef float f32x4 __attribute__((ext_vector_type(4)));
typedef unsigned short ushort8 __attribute__((ext_vector_type(8)));

typedef __attribute__((address_space(1))) char as1_char;
typedef __attribute__((address_space(3))) char as3_char;
#define GLDS16(g, l) __builtin_amdgcn_global_load_lds((as1_char*)(g), (as3_char*)(l), 16, 0, 0)

// AWQ nibble shift for unpacked col j within a word: AWQ_ORDER=(0,4,1,5,2,6,3,7)
// shift(j) = 4*AWQ_ORDER[j] = ((j&1)<<4) | ((j>>1)<<2)
static __device__ __forceinline__ int awq_shift(int j) {
  return ((j & 1) << 4) | ((j >> 1) << 2);
}

// fp32 -> bf16 bits, round-to-nearest-even (finite inputs only)
static __device__ __forceinline__ unsigned short f2bf(float f) {
  union { float f; uint32_t u; } c; c.f = f;
  uint32_t u = c.u;
  return (unsigned short)((u + 0x7FFFu + ((u >> 16) & 1u)) >> 16);
}

// ---------------- Stage 0: x fp32 -> bf16 ----------------
__global__ void k_cvt_x(const float* __restrict__ x, unsigned short* __restrict__ xb) {
  int i = blockIdx.x * blockDim.x + threadIdx.x;  // one thread per 8 elems, exact grid
  int base = i * 8;
  float4 v0 = *(const float4*)(x + base);
  float4 v1 = *(const float4*)(x + base + 4);
  ushort8 o;
  o[0] = f2bf(v0.x); o[1] = f2bf(v0.y); o[2] = f2bf(v0.z); o[3] = f2bf(v0.w);
  o[4] = f2bf(v1.x); o[5] = f2bf(v1.y); o[6] = f2bf(v1.z); o[7] = f2bf(v1.w);
  *(ushort8*)(xb + base) = o;
}

// ---------------- Stage 1: dequant W -> W^T bf16 [Nchunk][K] ----------------
// Tile: 64 k-rows x 128 n-cols (16 word-cols). Transpose through LDS so the
// output is k-contiguous (coalesced 128B row segments).
__global__ void k_dequant(const int* __restrict__ qw, const float* __restrict__ scales,
                          const int* __restrict__ qz, unsigned short* __restrict__ wt,
                          int n_base) {
  __shared__ int wlds[64][17];  // +1 pad kills phase-2 bank conflicts
  const int t = threadIdx.x;
  const int k0 = blockIdx.x * 64;            // 64 | k0 -> single scale-group per tile
  const int nb = blockIdx.y;                 // 128-col tile within this chunk
  const int n_glob0 = n_base + nb * 128;
  const int c0 = n_glob0 >> 3;
  const int g = k0 >> 7;
#pragma unroll
  for (int p = 0; p < 4; ++p) {              // load 64x16 packed words, coalesced
    int idx = p * 256 + t;
    int k = idx >> 4, c = idx & 15;
    wlds[k][c] = qw[(size_t)(k0 + k) * NC_DIM + c0 + c];
  }
  __syncthreads();
#pragma unroll
  for (int p = 0; p < 4; ++p) {              // each unit: 8 k-values of one n column
    int u = p * 256 + t;
    int k8 = u & 7;                          // fastest across lanes -> coalesced stores
    int nl = u >> 3;                         // 0..127 local n
    int j = nl & 7;
    int c = nl >> 3;
    int shift = awq_shift(j);
    float s = scales[(size_t)g * N_DIM + n_glob0 + nl];
    int zw = qz[(size_t)g * NC_DIM + c0 + c];
    float zs = (float)((zw >> shift) & 0xF) * s;
    ushort8 o;
#pragma unroll
    for (int i = 0; i < 8; ++i) {
      int wv = wlds[k8 * 8 + i][c];
      int nib = (wv >> shift) & 0xF;
      o[i] = f2bf(fmaf((float)nib, s, -zs));
    }
    *(ushort8*)(wt + (size_t)(nb * 128 + nl) * K_DIM + k0 + k8 * 8) = o;
  }
}

// ---------------- Stage 2: bf16 GEMM, m97 structure ----------------
// C[M,N] += A[M,K] * Bt[N,K]^T.  128x128 tile, BK=32, 4 waves (2x2 of 64x64),
// global_load_lds width-16 staging, ds_read_b128 fragments, 16x16x32 MFMA.
__launch_bounds__(256, 2)
__global__ void k_gemm(const unsigned short* __restrict__ A,
                       const unsigned short* __restrict__ Bt,
                       float* __restrict__ C, int n_base) {
  __shared__ unsigned short As[128 * 32];
  __shared__ unsigned short Bs[128 * 32];
  const int tid = threadIdx.x;
  const int lane = tid & 63;
  const int w = tid >> 6;
  const int wr = w >> 1, wc = w & 1;
  const int m0 = blockIdx.x * 128;
  const int nb0 = blockIdx.y * 128;          // chunk-local col base
  const int lrow = lane >> 2;                // 0..15 (row within 16-row stripe)
  const int lk = lane & 3;                   // 16B chunk within 64B row

  f32x4 acc[4][4] = {};

  const size_t a_row0 = (size_t)(m0 + w * 32) * K_DIM;
  const size_t b_row0 = (size_t)(nb0 + w * 32) * K_DIM;

  for (int kt = 0; kt < K_DIM / 32; ++kt) {
    const int k0 = kt * 32;
#pragma unroll
    for (int i = 0; i < 2; ++i) {
      const unsigned short* ga = A + a_row0 + (size_t)(i * 16 + lrow) * K_DIM + k0 + lk * 8;
      GLDS16(ga, &As[(w * 32 + i * 16) * 32]);
      const unsigned short* gb = Bt + b_row0 + (size_t)(i * 16 + lrow) * K_DIM + k0 + lk * 8;
      GLDS16(gb, &Bs[(w * 32 + i * 16) * 32]);
    }
    __syncthreads();  // drains vmcnt(0): staged tiles visible

    bf16x8 af[4], bfr[4];
#pragma unroll
    for (int mi = 0; mi < 4; ++mi)
      af[mi] = *(const bf16x8*)&As[(wr * 64 + mi * 16 + (lane & 15)) * 32 + (lane >> 4) * 8];
#pragma unroll
    for (int ni = 0; ni < 4; ++ni)
      bfr[ni] = *(const bf16x8*)&Bs[(wc * 64 + ni * 16 + (lane & 15)) * 32 + (lane >> 4) * 8];
#pragma unroll
    for (int mi = 0; mi < 4; ++mi)
#pragma unroll
      for (int ni = 0; ni < 4; ++ni)
        acc[mi][ni] = __builtin_amdgcn_mfma_f32_16x16x32_bf16(af[mi], bfr[ni], acc[mi][ni], 0, 0, 0);
    __syncthreads();  // protect LDS before next-iter overwrite
  }

  // Epilogue: C/D layout (16x16): col = lane&15, row = (lane>>4)*4 + r  [m89]
  const int crow_base = m0 + wr * 64 + (lane >> 4) * 4;
  const int ccol = n_base + nb0 + wc * 64 + (lane & 15);
#pragma unroll
  for (int mi = 0; mi < 4; ++mi)
#pragma unroll
    for (int ni = 0; ni < 4; ++ni)
#pragma unroll
      for (int r = 0; r < 4; ++r)
        C[(size_t)(crow_base + mi * 16 + r) * N_DIM + ccol + ni * 16] = acc[mi][ni][r];
}

// ---------------- Fallback: naive fused (only if ws too small) ----------------
__global__ void k_fallback(const float* __restrict__ x, const int* __restrict__ qw,
                           const float* __restrict__ scales, const int* __restrict__ qz,
                           float* __restrict__ C) {
  int t = blockIdx.x * 256 + threadIdx.x;
  int m = t / NC_DIM;
  int c = t % NC_DIM;
  float acc[8];
#pragma unroll
  for (int j = 0; j < 8; ++j) acc[j] = 0.f;
  for (int g = 0; g < G_DIM; ++g) {
    int zw = qz[(size_t)g * NC_DIM + c];
    float sj[8], zsj[8];
#pragma unroll
    for (int j = 0; j < 8; ++j) {
      int shift = awq_shift(j);
      sj[j] = scales[(size_t)g * N_DIM + c * 8 + j];
      zsj[j] = (float)((zw >> shift) & 0xF) * sj[j];
    }
    for (int k = g * GS; k < (g + 1) * GS; ++k) {
      float xv = x[(size_t)m * K_DIM + k];
      int wv = qw[(size_t)k * NC_DIM + c];
#pragma unroll
      for (int j = 0; j < 8; ++j) {
        float dq = fmaf((float)((wv >> awq_shift(j)) & 0xF), sj[j], -zsj[j]);
        acc[j] = fmaf(xv, dq, acc[j]);
      }
    }
  }
#pragma unroll
  for (int j = 0; j < 8; ++j)
    C[(size_t)m * N_DIM + c * 8 + j] = acc[j];
}

extern "C" void kernel_launch(void* const* d_in, const int* in_sizes, int n_in,
                              void* d_out, int out_size, void* d_ws, size_t ws_size,
                              hipStream_t stream) {
  (void)in_sizes; (void)n_in; (void)out_size;
  const float* x = (const float*)d_in[0];
  const int* qw = (const int*)d_in[1];
  const float* scales = (const float*)d_in[2];
  const int* qz = (const int*)d_in[3];
  float* C = (float*)d_out;

  const size_t xb_bytes = (size_t)M_DIM * K_DIM * 2;
  size_t avail = ws_size > xb_bytes ? ws_size - xb_bytes : 0;
  int nc_cols = (int)(avail / ((size_t)K_DIM * 2));
  int nchunk = (nc_cols / 128) * 128;
  if (nchunk > N_DIM) nchunk = N_DIM;

  if (nchunk >= 128) {
    unsigned short* xb = (unsigned short*)d_ws;
    unsigned short* wt = (unsigned short*)((char*)d_ws + xb_bytes);
    k_cvt_x<<<(M_DIM * K_DIM) / (256 * 8), 256, 0, stream>>>(x, xb);
    for (int n_base = 0; n_base < N_DIM; n_base += nchunk) {
      int cur = N_DIM - n_base; if (cur > nchunk) cur = nchunk;  // multiple of 128
      dim3 gd(K_DIM / 64, cur / 128);
      k_dequant<<<gd, 256, 0, stream>>>(qw, scales, qz, wt, n_base);
      dim3 gg(M_DIM / 128, cur / 128);
      k_gemm<<<gg, 256, 0, stream>>>(xb, wt, C, n_base);
    }
  } else {
    k_fallback<<<(M_DIM * NC_DIM) / 256, 256, 0, stream>>>(x, qw, scales, qz, C);
  }
}

// Round 2
// 131.280 us; speedup vs baseline: 1.2200x; 1.2200x over previous
//
#include <hip/hip_runtime.h>
#include <stdint.h>

// AWQGemm: x[1024,4096] f32, qweight[4096,1376] i32, scales[32,11008] f32,
// qzeros[32,1376] i32 -> C[1024,11008] f32
#define M_DIM 1024
#define K_DIM 4096
#define N_DIM 11008
#define NC_DIM 1376
#define G_DIM 32
#define GS 128

typedef __bf16 bf16x8 __attribute__((ext_vector_type(8)));
typedef float f32x4 __attribute__((ext_vector_type(4)));
typedef unsigned short ushort8 __attribute__((ext_vector_type(8)));

typedef __attribute__((address_space(1))) char as1_char;
typedef __attribute__((address_space(3))) char as3_char;
#define GLDS16(g, l) __builtin_amdgcn_global_load_lds((as1_char*)(g), (as3_char*)(l), 16, 0, 0)

static __device__ __forceinline__ int awq_shift(int j) {
  return ((j & 1) << 4) | ((j >> 1) << 2);
}

// fp32 -> bf16 bits, RNE
static __device__ __forceinline__ unsigned short f2bf(float f) {
  union { float f; uint32_t u; } c; c.f = f;
  uint32_t u = c.u;
  return (unsigned short)((u + 0x7FFFu + ((u >> 16) & 1u)) >> 16);
}

// ---------------- Stage 0: x fp32 -> bf16 ----------------
__global__ void k_cvt_x(const float* __restrict__ x, unsigned short* __restrict__ xb) {
  int i = blockIdx.x * blockDim.x + threadIdx.x;
  int base = i * 8;
  float4 v0 = *(const float4*)(x + base);
  float4 v1 = *(const float4*)(x + base + 4);
  ushort8 o;
  o[0] = f2bf(v0.x); o[1] = f2bf(v0.y); o[2] = f2bf(v0.z); o[3] = f2bf(v0.w);
  o[4] = f2bf(v1.x); o[5] = f2bf(v1.y); o[6] = f2bf(v1.z); o[7] = f2bf(v1.w);
  *(ushort8*)(xb + base) = o;
}

// ---------------- Stage 1: dequant W -> W^T bf16 [N][K] ----------------
__global__ void k_dequant(const int* __restrict__ qw, const float* __restrict__ scales,
                          const int* __restrict__ qz, unsigned short* __restrict__ wt) {
  __shared__ int wlds[64][17];
  const int t = threadIdx.x;
  const int k0 = blockIdx.x * 64;
  const int nb = blockIdx.y;
  const int n_glob0 = nb * 128;
  const int c0 = n_glob0 >> 3;
  const int g = k0 >> 7;
#pragma unroll
  for (int p = 0; p < 4; ++p) {
    int idx = p * 256 + t;
    int k = idx >> 4, c = idx & 15;
    wlds[k][c] = qw[(size_t)(k0 + k) * NC_DIM + c0 + c];
  }
  __syncthreads();
#pragma unroll
  for (int p = 0; p < 4; ++p) {
    int u = p * 256 + t;
    int k8 = u & 7;
    int nl = u >> 3;
    int j = nl & 7;
    int c = nl >> 3;
    int shift = awq_shift(j);
    float s = scales[(size_t)g * N_DIM + n_glob0 + nl];
    int zw = qz[(size_t)g * NC_DIM + c0 + c];
    float zs = (float)((zw >> shift) & 0xF) * s;
    ushort8 o;
#pragma unroll
    for (int i = 0; i < 8; ++i) {
      int wv = wlds[k8 * 8 + i][c];
      int nib = (wv >> shift) & 0xF;
      o[i] = f2bf(fmaf((float)nib, s, -zs));
    }
    *(ushort8*)(wt + (size_t)(nb * 128 + nl) * K_DIM + k0 + k8 * 8) = o;
  }
}

// ---------------- Stage 2: 256x256 8-phase bf16 GEMM ----------------
// 8 waves (2M x 4N), BK=64, NT=64 K-tiles. LDS: 2 buffers x 4 regions
// (A0,A1,B0,B1; 128 rows x 128B each, 16KB). Per K-tile 4 phases:
//   p0: ds_read Alo(8)+Blo(4); stage A1(t+1); BAR; MFMA Q(Alo,Blo); BAR
//   p1: ds_read Bhi(4);        stage B1(t+1); BAR; MFMA Q(Alo,Bhi); BAR
//   p2: ds_read Ahi(8);        stage B0(t+2); BAR; MFMA Q(Ahi,Bhi); BAR
//   p3: (no reads);            stage A0(t+2); BAR; MFMA Q(Ahi,Blo); vmcnt; BAR
// Race analysis (region last-read phase -> overwrite-issue phase, barrier between):
//   A regions read p0,p2; overwritten (t+2) at p3 of same tile.     p2 < p3 OK
//   B regions read p0,p1; overwritten (t+2) at p2 of same tile.     p1 < p2 OK
//   buf^1 regions (tile t+1 stages at p0,p1) free since tile t-1.            OK
// vmcnt(4) at p3: tile t+1's last half staged at p1; 2 phases x 2 loads after
// -> <=4 outstanding guarantees all of t+1 landed before next tile's reads.
// Swizzle: kbyte ^= (row&7)<<4 (bits 4-6) applied on BOTH the pre-swizzled
// global source (linear LDS dest) and the ds_read address (rule #21).
#define BK 64
#define NT (K_DIM / BK)
#define REG_BYTES 16384

__device__ __forceinline__ void stage_half(const unsigned short* __restrict__ src, int row0, int T,
                                           unsigned char* lds_region, int w, int lane) {
  const int kb = (((lane & 7) ^ ((lane >> 3) & 7)) << 4);  // pre-swizzled source k-byte
  const int row = w * 16 + (lane >> 3);
  const unsigned short* g = src + (size_t)(row0 + row) * K_DIM + T * 64 + (kb >> 1);
  unsigned char* l = lds_region + w * 2048;  // wave-uniform; HW adds lane*16
  GLDS16(g, l);
  GLDS16(g + (size_t)8 * K_DIM, l + 1024);
}

#define RD(base, off) (*(const bf16x8*)((const unsigned char*)(base) + (off)))
#define MFMA16(a, b, c) __builtin_amdgcn_mfma_f32_16x16x32_bf16((a), (b), (c), 0, 0, 0)

__launch_bounds__(512, 2)
__global__ void k_gemm8(const unsigned short* __restrict__ A,
                        const unsigned short* __restrict__ Bt,
                        float* __restrict__ C) {
  __shared__ __attribute__((aligned(16))) unsigned char LDS[131072];

  const int tid = threadIdx.x;
  const int lane = tid & 63;
  const int w = tid >> 6;       // 0..7
  const int wm = w >> 2;        // 0..1  (M half)
  const int wn = w & 3;         // 0..3  (N quarter)
  const int u = lane & 15;
  const int h = lane >> 4;      // 0..3
  const int xor16 = (lane & 7) << 4;
  const int kpos0 = (h * 16) ^ xor16;         // ks=0 swizzled k-byte
  const int kpos1 = (64 + h * 16) ^ xor16;    // ks=1
  const int aoff = u * 128;

  // bijective XCD swizzle: nwg=172 = 8*21+4
  const int orig = blockIdx.x;
  const int xcd = orig & 7, loc = orig >> 3;
  const int qq = 21, rr = 4;
  const int swz = (xcd < rr) ? xcd * (qq + 1) + loc : rr * (qq + 1) + (xcd - rr) * qq + loc;
  const int m0 = (swz & 3) * 256;    // M fastest: 4 row-tiles share a B panel per XCD chunk
  const int nb0 = (swz >> 2) * 256;

  f32x4 acc[8][4] = {};

  // ---- prologue: tile0 all 4 halves, then B0(1), A0(1); vmcnt(4); barrier
  stage_half(A,  m0,        0, LDS + 0 * REG_BYTES, w, lane);            // A0(0)
  stage_half(A,  m0 + 128,  0, LDS + 1 * REG_BYTES, w, lane);            // A1(0)
  stage_half(Bt, nb0,       0, LDS + 2 * REG_BYTES, w, lane);            // B0(0)
  stage_half(Bt, nb0 + 128, 0, LDS + 3 * REG_BYTES, w, lane);            // B1(0)
  stage_half(Bt, nb0,       1, LDS + 65536 + 2 * REG_BYTES, w, lane);    // B0(1)
  stage_half(A,  m0,        1, LDS + 65536 + 0 * REG_BYTES, w, lane);    // A0(1)
  asm volatile("s_waitcnt vmcnt(4)" ::: "memory");
  __builtin_amdgcn_s_barrier();

#pragma unroll 2
  for (int t = 0; t < NT; ++t) {
    const int cur = t & 1;
    unsigned char* bufc = LDS + cur * 65536;
    unsigned char* bufn = LDS + (cur ^ 1) * 65536;
    const unsigned char* rA = bufc + wm * REG_BYTES;
    const unsigned char* rB = bufc + (2 + (wn >> 1)) * REG_BYTES;
    const int bsub = (wn & 1) * 8192;

    bf16x8 aR[4][2], bLo[2][2], bHi[2][2];

    // ---------- phase 0 ----------
#pragma unroll
    for (int mi = 0; mi < 4; ++mi) {
      aR[mi][0] = RD(rA, mi * 2048 + aoff + kpos0);
      aR[mi][1] = RD(rA, mi * 2048 + aoff + kpos1);
    }
#pragma unroll
    for (int nf = 0; nf < 2; ++nf) {
      bLo[nf][0] = RD(rB, bsub + nf * 2048 + aoff + kpos0);
      bLo[nf][1] = RD(rB, bsub + nf * 2048 + aoff + kpos1);
    }
    if (t + 1 < NT) stage_half(A, m0 + 128, t + 1, bufn + 1 * REG_BYTES, w, lane);  // A1(t+1)
    __builtin_amdgcn_s_barrier();
    __builtin_amdgcn_s_setprio(1);
#pragma unroll
    for (int mi = 0; mi < 4; ++mi)
#pragma unroll
      for (int nf = 0; nf < 2; ++nf) {
        acc[mi][nf] = MFMA16(aR[mi][0], bLo[nf][0], acc[mi][nf]);
        acc[mi][nf] = MFMA16(aR[mi][1], bLo[nf][1], acc[mi][nf]);
      }
    __builtin_amdgcn_s_setprio(0);
    __builtin_amdgcn_s_barrier();

    // ---------- phase 1 ----------
#pragma unroll
    for (int nf = 0; nf < 2; ++nf) {
      bHi[nf][0] = RD(rB, bsub + (nf + 2) * 2048 + aoff + kpos0);
      bHi[nf][1] = RD(rB, bsub + (nf + 2) * 2048 + aoff + kpos1);
    }
    if (t + 1 < NT) stage_half(Bt, nb0 + 128, t + 1, bufn + 3 * REG_BYTES, w, lane);  // B1(t+1)
    __builtin_amdgcn_s_barrier();
    __builtin_amdgcn_s_setprio(1);
#pragma unroll
    for (int mi = 0; mi < 4; ++mi)
#pragma unroll
      for (int nf = 0; nf < 2; ++nf) {
        acc[mi][nf + 2] = MFMA16(aR[mi][0], bHi[nf][0], acc[mi][nf + 2]);
        acc[mi][nf + 2] = MFMA16(aR[mi][1], bHi[nf][1], acc[mi][nf + 2]);
      }
    __builtin_amdgcn_s_setprio(0);
    __builtin_amdgcn_s_barrier();

    // ---------- phase 2 ----------
#pragma unroll
    for (int mi = 0; mi < 4; ++mi) {
      aR[mi][0] = RD(rA, (mi + 4) * 2048 + aoff + kpos0);
      aR[mi][1] = RD(rA, (mi + 4) * 2048 + aoff + kpos1);
    }
    if (t + 2 < NT) stage_half(Bt, nb0, t + 2, bufc + 2 * REG_BYTES, w, lane);  // B0(t+2)
    __builtin_amdgcn_s_barrier();
    __builtin_amdgcn_s_setprio(1);
#pragma unroll
    for (int mi = 0; mi < 4; ++mi)
#pragma unroll
      for (int nf = 0; nf < 2; ++nf) {
        acc[mi + 4][nf + 2] = MFMA16(aR[mi][0], bHi[nf][0], acc[mi + 4][nf + 2]);
        acc[mi + 4][nf + 2] = MFMA16(aR[mi][1], bHi[nf][1], acc[mi + 4][nf + 2]);
      }
    __builtin_amdgcn_s_setprio(0);
    __builtin_amdgcn_s_barrier();

    // ---------- phase 3 ----------
    if (t + 2 < NT) stage_half(A, m0, t + 2, bufc + 0 * REG_BYTES, w, lane);  // A0(t+2)
    __builtin_amdgcn_s_barrier();
    __builtin_amdgcn_s_setprio(1);
#pragma unroll
    for (int mi = 0; mi < 4; ++mi)
#pragma unroll
      for (int nf = 0; nf < 2; ++nf) {
        acc[mi + 4][nf] = MFMA16(aR[mi][0], bLo[nf][0], acc[mi + 4][nf]);
        acc[mi + 4][nf] = MFMA16(aR[mi][1], bLo[nf][1], acc[mi + 4][nf]);
      }
    __builtin_amdgcn_s_setprio(0);
    if (t < NT - 2) {
      asm volatile("s_waitcnt vmcnt(4)" ::: "memory");
    } else {
      asm volatile("s_waitcnt vmcnt(0)" ::: "memory");
    }
    __builtin_amdgcn_s_barrier();
  }

  // ---- epilogue: C/D map col=lane&15, row=(lane>>4)*4+r [m89]
  const int crow0 = m0 + wm * 128 + h * 4;
  const int ccol0 = nb0 + wn * 64 + u;
#pragma unroll
  for (int mi = 0; mi < 8; ++mi)
#pragma unroll
    for (int nf = 0; nf < 4; ++nf)
#pragma unroll
      for (int r = 0; r < 4; ++r)
        C[(size_t)(crow0 + mi * 16 + r) * N_DIM + ccol0 + nf * 16] = acc[mi][nf][r];
}

// ---------------- Fallback (ws too small) ----------------
__global__ void k_fallback(const float* __restrict__ x, const int* __restrict__ qw,
                           const float* __restrict__ scales, const int* __restrict__ qz,
                           float* __restrict__ C) {
  int t = blockIdx.x * 256 + threadIdx.x;
  int m = t / NC_DIM;
  int c = t % NC_DIM;
  float acc[8];
#pragma unroll
  for (int j = 0; j < 8; ++j) acc[j] = 0.f;
  for (int g = 0; g < G_DIM; ++g) {
    int zw = qz[(size_t)g * NC_DIM + c];
    float sj[8], zsj[8];
#pragma unroll
    for (int j = 0; j < 8; ++j) {
      sj[j] = scales[(size_t)g * N_DIM + c * 8 + j];
      zsj[j] = (float)((zw >> awq_shift(j)) & 0xF) * sj[j];
    }
    for (int k = g * GS; k < (g + 1) * GS; ++k) {
      float xv = x[(size_t)m * K_DIM + k];
      int wv = qw[(size_t)k * NC_DIM + c];
#pragma unroll
      for (int j = 0; j < 8; ++j) {
        float dq = fmaf((float)((wv >> awq_shift(j)) & 0xF), sj[j], -zsj[j]);
        acc[j] = fmaf(xv, dq, acc[j]);
      }
    }
  }
#pragma unroll
  for (int j = 0; j < 8; ++j)
    C[(size_t)m * N_DIM + c * 8 + j] = acc[j];
}

extern "C" void kernel_launch(void* const* d_in, const int* in_sizes, int n_in,
                              void* d_out, int out_size, void* d_ws, size_t ws_size,
                              hipStream_t stream) {
  (void)in_sizes; (void)n_in; (void)out_size;
  const float* x = (const float*)d_in[0];
  const int* qw = (const int*)d_in[1];
  const float* scales = (const float*)d_in[2];
  const int* qz = (const int*)d_in[3];
  float* C = (float*)d_out;

  const size_t xb_bytes = (size_t)M_DIM * K_DIM * 2;
  const size_t wt_bytes = (size_t)N_DIM * K_DIM * 2;

  if (ws_size >= xb_bytes + wt_bytes) {
    unsigned short* xb = (unsigned short*)d_ws;
    unsigned short* wt = (unsigned short*)((char*)d_ws + xb_bytes);
    k_cvt_x<<<(M_DIM * K_DIM) / (256 * 8), 256, 0, stream>>>(x, xb);
    dim3 gd(K_DIM / 64, N_DIM / 128);
    k_dequant<<<gd, 256, 0, stream>>>(qw, scales, qz, wt);
    k_gemm8<<<(M_DIM / 256) * (N_DIM / 256), 512, 0, stream>>>(xb, wt, C);
  } else {
    k_fallback<<<(M_DIM * NC_DIM) / 256, 256, 0, stream>>>(x, qw, scales, qz, C);
  }
}